// Round 3
// baseline (78.518 us; speedup 1.0000x reference)
//
#include <hip/hip_runtime.h>

#define NB 32
#define NK 8
#define IN_DIM 512
#define DLAT 128
#define DTOT 1024
#define ZS 516     // padded z row stride in floats (516 % 32 = 4 -> no bank conflict)
#define PS 132     // padded psi row stride

// One fused kernel. 512 blocks x 1024 threads; block = (batch b, slice s).
// Each block computes its batch's full evolved/normalized state `a` (16x
// redundant per batch -- cheap, deterministic, bitwise identical across
// blocks) and writes rows [s*64, s*64+64) of out[b] = a a^T + diag*I.
__global__ __launch_bounds__(1024) void qsfm_fused(
    const float* __restrict__ z, const float* __restrict__ t,
    const float* __restrict__ W_proj, const float* __restrict__ b_proj,
    const float* __restrict__ W1, const float* __restrict__ b1,
    const float* __restrict__ W2, const float* __restrict__ b2,
    float4* __restrict__ out)
{
    __shared__ float zs[NK * ZS];      // staged z, padded
    __shared__ float psi_s[NK * PS];   // normalized state, padded
    __shared__ float a_s[DTOT];        // final rank-1 vector
    __shared__ float wpart[16 * 8];    // per-wave per-shot norm partials
    __shared__ float npart[16];        // per-wave ||y||^2 partials
    __shared__ float norm2[NK];
    __shared__ float f_s[8];
    __shared__ float lam_sh, n2_sh, diag_sh;

    const int b   = blockIdx.x >> 4;
    const int s   = blockIdx.x & 15;
    const int tid = threadIdx.x;
    const int lane = tid & 63;
    const int w    = tid >> 6;

    // ---- stage z (8 shots x 512 floats), coalesced, padded stride
    {
        const float4 v = ((const float4*)(z + (size_t)b * NK * IN_DIM))[tid];
        const int sh = tid >> 7, pos = tid & 127;
        *(float4*)(zs + sh * ZS + pos * 4) = v;
    }
    __syncthreads();

    // ---- projection: thread owns (shot = tid&7, o = tid>>3).
    // 8 lanes share one W row (broadcast); LDS z reads conflict-free (pad).
    const int shot = tid & 7;
    const int o    = tid >> 3;
    float acc = 0.f;
    {
        const float4* __restrict__ wrow = (const float4*)(W_proj + (size_t)o * IN_DIM);
        const float* zrow = zs + shot * ZS;
        #pragma unroll 4
        for (int i = 0; i < IN_DIM / 4; ++i) {
            const float4 wv = wrow[i];
            const float4 zv = *(const float4*)(zrow + i * 4);
            acc += wv.x * zv.x + wv.y * zv.y + wv.z * zv.z + wv.w * zv.w;
        }
    }
    const float psi = acc + b_proj[o];

    // ---- per-shot ||psi||^2: reduce lanes with equal (lane&7), then x-wave
    {
        float v = psi * psi;
        v += __shfl_xor(v, 8);
        v += __shfl_xor(v, 16);
        v += __shfl_xor(v, 32);
        if (lane < 8) wpart[w * 8 + lane] = v;
    }
    __syncthreads();
    if (tid < 8) {                     // wave 0: finish shot norms
        float ss = 0.f;
        #pragma unroll
        for (int q = 0; q < 16; ++q) ss += wpart[q * 8 + tid];
        norm2[tid] = ss;
    } else if (w == 1) {               // wave 1 concurrently: lambda(t) MLP
        const float tb = t[b];
        const float h0 = tb * W1[lane] + b1[lane];
        const float h1 = tb * W1[lane + 64] + b1[lane + 64];
        float val = W2[lane]      * (h0 / (1.f + expf(-h0)))
                  + W2[lane + 64] * (h1 / (1.f + expf(-h1)));
        #pragma unroll
        for (int m = 32; m; m >>= 1) val += __shfl_xor(val, m);
        if (lane == 0) lam_sh = tanhf(val + b2[0]) * 0.1f;
    }
    __syncthreads();

    // ---- normalize shot, pre-scale 1/sqrt(K); store state
    psi_s[shot * PS + o] =
        psi / fmaxf(sqrtf(norm2[shot]), 1e-8f) * 0.35355339059327373f;

    // ---- E = exp(-lam*H_idx) is a symmetric circulant:
    // f(d) = 1/8 sum_m exp(-2 lam cos(pi m/4)) cos(pi m d/4)
    if (tid < 8) {
        const float c4[8] = {1.f, 0.70710678118654752f, 0.f, -0.70710678118654752f,
                             -1.f, -0.70710678118654752f, 0.f, 0.70710678118654752f};
        const float lam = lam_sh;
        float a8 = 0.f;
        #pragma unroll
        for (int m = 0; m < 8; ++m)
            a8 += expf(-2.f * lam * c4[m]) * c4[(m * tid) & 7];
        f_s[tid] = 0.125f * a8;
    }
    __syncthreads();

    // ---- y = kron(E, I_128) @ state ; ||y||^2
    const int kk = tid >> 7, oo = tid & 127;
    float y = 0.f;
    #pragma unroll
    for (int kp = 0; kp < NK; ++kp)
        y += f_s[(kk - kp) & 7] * psi_s[kp * PS + oo];
    {
        float v = y * y;
        #pragma unroll
        for (int m = 32; m; m >>= 1) v += __shfl_xor(v, m);
        if (lane == 0) npart[w] = v;
    }
    __syncthreads();
    if (tid < 16) {
        float sv = npart[tid];
        sv += __shfl_xor(sv, 1); sv += __shfl_xor(sv, 2);
        sv += __shfl_xor(sv, 4); sv += __shfl_xor(sv, 8);
        if (tid == 0) n2_sh = sv;
    }
    __syncthreads();

    // ---- epilogue algebra: out[i][j] = a_i a_j + delta_ij * 1e-7/tr2,
    //      a = y / sqrt(n2c*tr2), tr2 = n2/n2c + 1024e-7
    const float n2  = n2_sh;
    const float n2c = fmaxf(n2, 1e-8f);
    const float tr2 = n2 / n2c + (float)DTOT * 1e-7f;
    const float sc  = 1.f / sqrtf(n2c * tr2);
    a_s[tid] = y * sc;
    if (tid == 0) diag_sh = 1e-7f / tr2;
    __syncthreads();

    // ---- write 64-row slice of out[b] = a a^T (+diag), coalesced float4
    const float dd = diag_sh;
    const int i0 = s * 64;
    float4* __restrict__ outb = out + ((size_t)b << 18);   // b*1024*256
    #pragma unroll 4
    for (int it = 0; it < 16; ++it) {
        const int idx = it * 1024 + tid;
        const int j4 = idx & 255;
        const int i  = i0 + (idx >> 8);
        const float  ai = a_s[i];
        const float4 aj = ((const float4*)a_s)[j4];
        float4 v4;
        v4.x = ai * aj.x; v4.y = ai * aj.y; v4.z = ai * aj.z; v4.w = ai * aj.w;
        const int dj = i - j4 * 4;
        if (dj >= 0 && dj < 4) {
            if      (dj == 0) v4.x += dd;
            else if (dj == 1) v4.y += dd;
            else if (dj == 2) v4.z += dd;
            else              v4.w += dd;
        }
        outb[(size_t)i * 256 + j4] = v4;
    }
}

extern "C" void kernel_launch(void* const* d_in, const int* in_sizes, int n_in,
                              void* d_out, int out_size, void* d_ws, size_t ws_size,
                              hipStream_t stream) {
    (void)in_sizes; (void)n_in; (void)out_size; (void)d_ws; (void)ws_size;
    const float* z  = (const float*)d_in[0];
    const float* t  = (const float*)d_in[1];
    const float* Wp = (const float*)d_in[2];
    const float* bp = (const float*)d_in[3];
    const float* W1 = (const float*)d_in[4];
    const float* b1 = (const float*)d_in[5];
    const float* W2 = (const float*)d_in[6];
    const float* b2 = (const float*)d_in[7];

    qsfm_fused<<<NB * 16, 1024, 0, stream>>>(z, t, Wp, bp, W1, b1, W2, b2,
                                             (float4*)d_out);
}

// Round 4
// 49.049 us; speedup vs baseline: 1.6008x; 1.6008x over previous
//
#include <hip/hip_runtime.h>

#define NB 32
#define NK 8
#define IN_DIM 512
#define DLAT 128
#define DTOT 1024
#define PS 132   // padded psi row stride (floats)

// ---------------------------------------------------------------------------
// Kernel 1: one block per batch (32 blocks x 1024 threads).
// Wave w (of 16): shot = w>>1, rows o in [ (w&1)*64, +64 ).
// Each W row (512 f) is read by the whole wave in 2 coalesced dwordx4 loads
// (lane l holds elements l*8..l*8+7); z slice is register-resident.
// ---------------------------------------------------------------------------
__global__ __launch_bounds__(1024) void qsfm_avec(
    const float* __restrict__ z, const float* __restrict__ t,
    const float* __restrict__ W_proj, const float* __restrict__ b_proj,
    const float* __restrict__ W1, const float* __restrict__ b1,
    const float* __restrict__ W2, const float* __restrict__ b2,
    float* __restrict__ a_out, float* __restrict__ diag_out)
{
    __shared__ float psi_s[NK * PS];
    __shared__ float wpart[16];
    __shared__ float norm2[NK];
    __shared__ float f_s[8];
    __shared__ float lam_sh, n2_sh;

    const int b    = blockIdx.x;
    const int tid  = threadIdx.x;
    const int lane = tid & 63;
    const int w    = tid >> 6;
    const int shot = w >> 1;
    const int o0   = (w & 1) * 64;

    // ---- register-resident z slice for this wave's shot
    const float4* __restrict__ zr =
        (const float4*)(z + ((size_t)b * NK + shot) * IN_DIM + lane * 8);
    const float4 z0 = zr[0], z1 = zr[1];

    // ---- 64 projection rows per wave; row o0+r's dot kept by lane r
    float keep = 0.f;
    #pragma unroll 4
    for (int r = 0; r < 64; ++r) {
        const float4* __restrict__ wr =
            (const float4*)(W_proj + (size_t)(o0 + r) * IN_DIM + lane * 8);
        const float4 w0 = wr[0], w1 = wr[1];
        float p = w0.x * z0.x + w0.y * z0.y + w0.z * z0.z + w0.w * z0.w
                + w1.x * z1.x + w1.y * z1.y + w1.z * z1.z + w1.w * z1.w;
        #pragma unroll
        for (int m = 32; m; m >>= 1) p += __shfl_xor(p, m);
        if (lane == r) keep = p;
    }
    psi_s[shot * PS + o0 + lane] = keep + b_proj[o0 + lane];
    __syncthreads();

    // ---- per-shot ||psi||^2 (thread t -> shot t>>7, o t&127)
    {
        const int s = tid >> 7, o = tid & 127;
        const float v = psi_s[s * PS + o];
        float q = v * v;
        #pragma unroll
        for (int m = 32; m; m >>= 1) q += __shfl_xor(q, m);
        if (lane == 0) wpart[w] = q;
    }
    __syncthreads();
    if (tid < NK) {                    // wave 0: finish shot norms
        norm2[tid] = wpart[2 * tid] + wpart[2 * tid + 1];
    } else if (w == 1) {               // wave 1 concurrently: lambda(t) MLP
        const float tb = t[b];
        const float h0 = tb * W1[lane] + b1[lane];
        const float h1 = tb * W1[lane + 64] + b1[lane + 64];
        float val = W2[lane]      * (h0 / (1.f + expf(-h0)))
                  + W2[lane + 64] * (h1 / (1.f + expf(-h1)));
        #pragma unroll
        for (int m = 32; m; m >>= 1) val += __shfl_xor(val, m);
        if (lane == 0) lam_sh = tanhf(val + b2[0]) * 0.1f;
    }
    __syncthreads();

    // ---- normalize (reads norm2) and circulant coefficients (reads lam_sh)
    {
        const int s = tid >> 7, o = tid & 127;
        psi_s[s * PS + o] = psi_s[s * PS + o]
            / fmaxf(sqrtf(norm2[s]), 1e-8f) * 0.35355339059327373f;  // 1/sqrt(8)
    }
    if (tid < 8) {
        // E = exp(-lam*H_idx), C8 circulant: f(d) = 1/8 sum_m
        //   exp(-2 lam cos(pi m/4)) cos(pi m d/4)
        const float c4[8] = {1.f, 0.70710678118654752f, 0.f, -0.70710678118654752f,
                             -1.f, -0.70710678118654752f, 0.f, 0.70710678118654752f};
        const float lam = lam_sh;
        float a8 = 0.f;
        #pragma unroll
        for (int m = 0; m < 8; ++m)
            a8 += expf(-2.f * lam * c4[m]) * c4[(m * tid) & 7];
        f_s[tid] = 0.125f * a8;
    }
    __syncthreads();

    // ---- y = kron(E, I_128) @ state ; ||y||^2
    const int k = tid >> 7, o = tid & 127;
    float y = 0.f;
    #pragma unroll
    for (int kp = 0; kp < NK; ++kp)
        y += f_s[(k - kp) & 7] * psi_s[kp * PS + o];
    {
        float q = y * y;
        #pragma unroll
        for (int m = 32; m; m >>= 1) q += __shfl_xor(q, m);
        if (lane == 0) wpart[w] = q;
    }
    __syncthreads();
    if (tid < 16) {
        float sv = wpart[tid];
        sv += __shfl_xor(sv, 1); sv += __shfl_xor(sv, 2);
        sv += __shfl_xor(sv, 4); sv += __shfl_xor(sv, 8);
        if (tid == 0) n2_sh = sv;
    }
    __syncthreads();

    // ---- epilogue algebra: out[i][j] = a_i a_j + delta_ij * 1e-7/tr2,
    //      a = y / sqrt(n2c*tr2), tr2 = n2/n2c + 1024e-7
    const float n2  = n2_sh;
    const float n2c = fmaxf(n2, 1e-8f);
    const float tr2 = n2 / n2c + (float)DTOT * 1e-7f;
    const float sc  = 1.f / sqrtf(n2c * tr2);
    a_out[b * DTOT + tid] = y * sc;
    if (tid == 0) diag_out[b] = 1e-7f / tr2;
}

// ---------------------------------------------------------------------------
// Kernel 2: out[b,i,j] = a[b,i]*a[b,j] (+ diag[b] on the diagonal).
// Pure streaming write of 128 MB; a (128 KB) stays L2-resident.
// ---------------------------------------------------------------------------
__global__ __launch_bounds__(256) void qsfm_outer(
    const float* __restrict__ a, const float* __restrict__ diag,
    float4* __restrict__ out)
{
    const int total4 = NB * DTOT * (DTOT / 4);     // 8388608
    const int stride = gridDim.x * blockDim.x;
    for (int idx4 = blockIdx.x * blockDim.x + threadIdx.x; idx4 < total4;
         idx4 += stride) {
        const int j4 = idx4 & (DTOT / 4 - 1);      // float4 col
        const int i  = (idx4 >> 8) & (DTOT - 1);   // row
        const int b  = idx4 >> 18;                 // / (1024*256)
        const float ai = a[b * DTOT + i];
        const float4 aj = *(const float4*)(a + b * DTOT + j4 * 4);
        float4 v;
        v.x = ai * aj.x; v.y = ai * aj.y; v.z = ai * aj.z; v.w = ai * aj.w;
        const int dj = i - j4 * 4;
        if (dj >= 0 && dj < 4) {
            const float dd = diag[b];
            if      (dj == 0) v.x += dd;
            else if (dj == 1) v.y += dd;
            else if (dj == 2) v.z += dd;
            else              v.w += dd;
        }
        out[idx4] = v;
    }
}

extern "C" void kernel_launch(void* const* d_in, const int* in_sizes, int n_in,
                              void* d_out, int out_size, void* d_ws, size_t ws_size,
                              hipStream_t stream) {
    (void)in_sizes; (void)n_in; (void)out_size; (void)ws_size;
    const float* z  = (const float*)d_in[0];
    const float* t  = (const float*)d_in[1];
    const float* Wp = (const float*)d_in[2];
    const float* bp = (const float*)d_in[3];
    const float* W1 = (const float*)d_in[4];
    const float* b1 = (const float*)d_in[5];
    const float* W2 = (const float*)d_in[6];
    const float* b2 = (const float*)d_in[7];

    float* ws   = (float*)d_ws;
    float* a    = ws;              // NB*DTOT floats
    float* diag = ws + NB * DTOT;  // NB floats

    qsfm_avec<<<NB, 1024, 0, stream>>>(z, t, Wp, bp, W1, b1, W2, b2, a, diag);
    qsfm_outer<<<2048, 256, 0, stream>>>(a, diag, (float4*)d_out);
}